// Round 1
// baseline (4025.231 us; speedup 1.0000x reference)
//
#include <hip/hip_runtime.h>
#include <hip/hip_bf16.h>

typedef __attribute__((ext_vector_type(8))) short short8;
typedef __attribute__((ext_vector_type(4))) float floatx4;

#define GLD16(g, l) __builtin_amdgcn_global_load_lds( \
    (__attribute__((address_space(1))) void*)(g),      \
    (__attribute__((address_space(3))) void*)(l), 16, 0, 0)

#define MFMA_BF16(a, b, c) __builtin_amdgcn_mfma_f32_16x16x32_bf16((a), (b), (c), 0, 0, 0)

__device__ __forceinline__ short f2bf(float f) {
  union { __hip_bfloat16 h; short s; } u;
  u.h = __float2bfloat16(f);
  return u.s;
}

// ---------------------------------------------------------------------------
// transpose + fp32->bf16 convert:  in fp32 [K][N]  ->  out bf16 [Npad][K]
// pad rows (n >= N) get zeros. K % 32 == 0, Npad % 32 == 0.
// ---------------------------------------------------------------------------
__global__ __launch_bounds__(256)
void transpose_convert(const float* __restrict__ in, short* __restrict__ out,
                       const int K, const int N, const int Npad) {
  __shared__ float tile[32][33];
  const int n0 = blockIdx.x * 32;
  const int k0 = blockIdx.y * 32;
  const int tx = threadIdx.x;  // 0..31
  const int ty = threadIdx.y;  // 0..7
#pragma unroll
  for (int i = 0; i < 4; ++i) {
    const int kk = ty + i * 8;
    const int nn = n0 + tx;
    tile[kk][tx] = (nn < N) ? in[(size_t)(k0 + kk) * N + nn] : 0.f;
  }
  __syncthreads();
#pragma unroll
  for (int i = 0; i < 4; ++i) {
    const int nn = ty + i * 8;
    out[(size_t)(n0 + nn) * K + k0 + tx] = f2bf(tile[tx][nn]);
  }
}

// ---------------------------------------------------------------------------
// embedding: x[row][c] = wte[idx[row]][c] + wpe[row % 1024][c]   (fp32)
// ---------------------------------------------------------------------------
__global__ __launch_bounds__(256)
void embed_kernel(const int* __restrict__ idx, const float* __restrict__ wte,
                  const float* __restrict__ wpe, float* __restrict__ x) {
  const int row = blockIdx.x;
  const int tok = idx[row];
  const int s = row & 1023;
  const float* wt = wte + (size_t)tok * 768;
  const float* wp = wpe + (size_t)s * 768;
  float* xr = x + (size_t)row * 768;
  for (int c = threadIdx.x; c < 768; c += 256) xr[c] = wt[c] + wp[c];
}

// ---------------------------------------------------------------------------
// layernorm: x fp32 [4096][768] -> h bf16, per-row block of 256 threads
// ---------------------------------------------------------------------------
__global__ __launch_bounds__(256)
void ln_kernel(const float* __restrict__ x, const float* __restrict__ g,
               const float* __restrict__ b, short* __restrict__ out) {
  const int row = blockIdx.x;
  const int t = threadIdx.x;
  const int wv = t >> 6, lane = t & 63;
  const float* xr = x + (size_t)row * 768;
  const float v0 = xr[t], v1 = xr[t + 256], v2 = xr[t + 512];
  __shared__ float red[4];
  float s = v0 + v1 + v2;
#pragma unroll
  for (int m = 1; m < 64; m <<= 1) s += __shfl_xor(s, m);
  if (lane == 0) red[wv] = s;
  __syncthreads();
  const float mean = (red[0] + red[1] + red[2] + red[3]) * (1.0f / 768.0f);
  __syncthreads();
  const float d0 = v0 - mean, d1 = v1 - mean, d2 = v2 - mean;
  float q = d0 * d0 + d1 * d1 + d2 * d2;
#pragma unroll
  for (int m = 1; m < 64; m <<= 1) q += __shfl_xor(q, m);
  if (lane == 0) red[wv] = q;
  __syncthreads();
  const float var = (red[0] + red[1] + red[2] + red[3]) * (1.0f / 768.0f);
  const float inv = rsqrtf(var + 1e-5f);
  short* orow = out + (size_t)row * 768;
  orow[t] = f2bf(d0 * inv * g[t] + b[t]);
  orow[t + 256] = f2bf(d1 * inv * g[t + 256] + b[t + 256]);
  orow[t + 512] = f2bf(d2 * inv * g[t + 512] + b[t + 512]);
}

// ---------------------------------------------------------------------------
// GEMM: C[M][N] = A[M][K](bf16) @ Bt[N][K]^T(bf16), fp32 acc, fused epilogues
// 128x128 tile, BK=32, 256 threads = 4 waves, each wave 64x64 (4x4 frags)
// ---------------------------------------------------------------------------
enum { EPI_QKV = 0, EPI_RESID = 1, EPI_GELU = 2, EPI_LM = 3 };

template <int EPI>
__global__ __launch_bounds__(256)
void gemm_kernel(const short* __restrict__ A, const short* __restrict__ Bt, const int K,
                 const float* __restrict__ bias0, const float* __restrict__ bias1,
                 const float* __restrict__ bias2, float* __restrict__ fout,
                 short* __restrict__ bout0, short* __restrict__ bout1,
                 short* __restrict__ bout2) {
  __shared__ short sA[128 * 32];
  __shared__ short sB[128 * 32];
  const int tid = threadIdx.x;
  const int wv = tid >> 6;
  const int lane = tid & 63;
  const int lrow = lane & 15;
  const int lk8 = lane >> 4;
  const int m0 = blockIdx.x * 128;
  const int n0 = blockIdx.y * 128;
  const int wm = (wv >> 1) * 64;
  const int wn = (wv & 1) * 64;

  floatx4 acc[4][4];
#pragma unroll
  for (int m = 0; m < 4; ++m)
#pragma unroll
    for (int n = 0; n < 4; ++n) acc[m][n] = {0.f, 0.f, 0.f, 0.f};

  const int e0 = tid * 8;
  const int r0 = e0 >> 5, c0 = e0 & 31;
  const int e1 = (256 + tid) * 8;
  const int r1 = e1 >> 5, c1 = e1 & 31;

  const short* Ab = A + (size_t)m0 * K;
  const short* Bb = Bt + (size_t)n0 * K;

  const int nk = K >> 5;
  for (int kt = 0; kt < nk; ++kt) {
    const int kb = kt << 5;
    GLD16(Ab + (size_t)r0 * K + kb + c0, sA + wv * 512);
    GLD16(Ab + (size_t)r1 * K + kb + c1, sA + 2048 + wv * 512);
    GLD16(Bb + (size_t)r0 * K + kb + c0, sB + wv * 512);
    GLD16(Bb + (size_t)r1 * K + kb + c1, sB + 2048 + wv * 512);
    __syncthreads();
    short8 af[4], bfv[4];
#pragma unroll
    for (int m = 0; m < 4; ++m)
      af[m] = *(const short8*)(sA + (wm + m * 16 + lrow) * 32 + lk8 * 8);
#pragma unroll
    for (int n = 0; n < 4; ++n)
      bfv[n] = *(const short8*)(sB + (wn + n * 16 + lrow) * 32 + lk8 * 8);
#pragma unroll
    for (int m = 0; m < 4; ++m)
#pragma unroll
      for (int n = 0; n < 4; ++n)
        acc[m][n] = MFMA_BF16(af[m], bfv[n], acc[m][n]);
    __syncthreads();
  }

#pragma unroll
  for (int m = 0; m < 4; ++m) {
#pragma unroll
    for (int n = 0; n < 4; ++n) {
#pragma unroll
      for (int r = 0; r < 4; ++r) {
        const float v = acc[m][n][r];
        const int gm = m0 + wm + m * 16 + lk8 * 4 + r;
        const int gn = n0 + wn + n * 16 + lrow;
        if (EPI == EPI_QKV) {
          // gn in [0,2304): 0..767 -> q (scaled 1/8), 768..1535 -> k, 1536.. -> v^T
          const int sec = (gn >= 1536) ? 2 : (gn >= 768 ? 1 : 0);
          const int nn = gn - sec * 768;
          const int hh = nn >> 6, dh = nn & 63;
          const int bb = gm >> 10, srow = gm & 1023;
          if (sec == 0) {
            bout0[(((size_t)(bb * 12 + hh) * 1024 + srow) << 6) + dh] =
                f2bf((v + bias0[nn]) * 0.125f);
          } else if (sec == 1) {
            bout1[(((size_t)(bb * 12 + hh) * 1024 + srow) << 6) + dh] =
                f2bf(v + bias1[nn]);
          } else {
            bout2[(((size_t)(bb * 12 + hh) * 64 + dh) << 10) + srow] =
                f2bf(v + bias2[nn]);
          }
        } else if (EPI == EPI_RESID) {
          float* xp = fout + (size_t)gm * 768 + gn;
          *xp = *xp + v + bias0[gn];
        } else if (EPI == EPI_GELU) {
          const float tt = v + bias0[gn];
          const float gl = 0.5f * tt * (1.f + erff(tt * 0.70710678118654752f));
          bout0[(size_t)gm * 3072 + gn] = f2bf(gl);
        } else {  // EPI_LM
          if (gn < 50257) fout[(size_t)gm * 50257 + gn] = v;
        }
      }
    }
  }
}

// ---------------------------------------------------------------------------
// flash attention (causal): q,k [48][1024][64] bf16 (q pre-scaled by 1/8),
// vt [48][64][1024] bf16 -> o [4096][768] bf16.
// grid (48, 16), block 256. wave w owns q-rows q0+w*16 .. +15.
// ---------------------------------------------------------------------------
__global__ __launch_bounds__(256)
void attn_kernel(const short* __restrict__ q, const short* __restrict__ k,
                 const short* __restrict__ vt, short* __restrict__ o) {
  __shared__ short sK[64 * 64];      // [key][dh], 16B-unit XOR-swizzled
  __shared__ short sV[64 * 64];      // [dh][key], swizzled
  __shared__ short sP[4][16 * 64];   // per-wave P, swizzled
  const int bh = blockIdx.x;
  const int qi = blockIdx.y;
  const int tid = threadIdx.x;
  const int wv = tid >> 6, lane = tid & 63;
  const int lrow = lane & 15, lk8 = lane >> 4;
  const int q0 = qi * 64;

  const short* qg = q + ((size_t)(bh * 1024 + q0 + wv * 16 + lrow)) * 64 + lk8 * 8;
  const short8 qf0 = *(const short8*)qg;
  const short8 qf1 = *(const short8*)(qg + 32);

  float m_run[4], lsum[4];
  floatx4 accO[4];
#pragma unroll
  for (int r = 0; r < 4; ++r) { m_run[r] = -1e30f; lsum[r] = 0.f; }
#pragma unroll
  for (int n = 0; n < 4; ++n) accO[n] = {0.f, 0.f, 0.f, 0.f};

  for (int t = 0; t <= qi; ++t) {
    const int k0 = t * 64;
#pragma unroll
    for (int i = 0; i < 2; ++i) {
      const int e = (i * 256 + tid) * 8;
      const int r = e >> 6, cc = e & 63;
      const int su = ((cc >> 3) ^ (r & 7)) << 3;
      *(short8*)(sK + r * 64 + su) =
          *(const short8*)(k + ((size_t)(bh * 1024 + k0 + r)) * 64 + cc);
      *(short8*)(sV + r * 64 + su) =
          *(const short8*)(vt + ((size_t)(bh * 64 + r)) * 1024 + k0 + cc);
    }
    __syncthreads();

    floatx4 accS[4];
#pragma unroll
    for (int n = 0; n < 4; ++n) accS[n] = {0.f, 0.f, 0.f, 0.f};
#pragma unroll
    for (int ks = 0; ks < 2; ++ks) {
      const short8 qf = ks ? qf1 : qf0;
      const int u = lk8 + ks * 4;
#pragma unroll
      for (int n = 0; n < 4; ++n) {
        const int key = n * 16 + lrow;
        const short8 kf = *(const short8*)(sK + key * 64 + ((u ^ (key & 7)) << 3));
        accS[n] = MFMA_BF16(qf, kf, accS[n]);
      }
    }

#pragma unroll
    for (int r = 0; r < 4; ++r) {
      const int qrow = q0 + wv * 16 + lk8 * 4 + r;
      float sv[4];
      float mx = -1e30f;
#pragma unroll
      for (int n = 0; n < 4; ++n) {
        float s = accS[n][r];
        const int key = k0 + n * 16 + lrow;
        s = (key > qrow) ? -1e30f : s;
        sv[n] = s;
        mx = fmaxf(mx, s);
      }
#pragma unroll
      for (int m = 1; m < 16; m <<= 1) mx = fmaxf(mx, __shfl_xor(mx, m));
      const float mnew = fmaxf(m_run[r], mx);
      const float sf = __expf(m_run[r] - mnew);
      m_run[r] = mnew;
      float rs = 0.f;
      const int prow = lk8 * 4 + r;
#pragma unroll
      for (int n = 0; n < 4; ++n) {
        const float pv = __expf(sv[n] - mnew);
        rs += pv;
        const int col = n * 16 + lrow;
        sP[wv][prow * 64 + (((col >> 3) ^ (prow & 7)) << 3) + (col & 7)] = f2bf(pv);
      }
#pragma unroll
      for (int m = 1; m < 16; m <<= 1) rs += __shfl_xor(rs, m);
      lsum[r] = lsum[r] * sf + rs;
#pragma unroll
      for (int n = 0; n < 4; ++n) accO[n][r] *= sf;
    }

#pragma unroll
    for (int ks = 0; ks < 2; ++ks) {
      const int u = lk8 + ks * 4;
      const short8 pf =
          *(const short8*)(&sP[wv][lrow * 64 + ((u ^ (lrow & 7)) << 3)]);
#pragma unroll
      for (int n = 0; n < 4; ++n) {
        const int dh = n * 16 + lrow;
        const short8 vf = *(const short8*)(sV + dh * 64 + ((u ^ (dh & 7)) << 3));
        accO[n] = MFMA_BF16(pf, vf, accO[n]);
      }
    }
    __syncthreads();
  }

  const int bb = bh / 12, hh = bh % 12;
#pragma unroll
  for (int n = 0; n < 4; ++n)
#pragma unroll
    for (int r = 0; r < 4; ++r) {
      const int row = q0 + wv * 16 + lk8 * 4 + r;
      const float ov = accO[n][r] / lsum[r];
      o[((size_t)(bb * 1024 + row)) * 768 + hh * 64 + n * 16 + lrow] = f2bf(ov);
    }
}

// ---------------------------------------------------------------------------
extern "C" void kernel_launch(void* const* d_in, const int* in_sizes, int n_in,
                              void* d_out, int out_size, void* d_ws, size_t ws_size,
                              hipStream_t stream) {
  const int* idx = (const int*)d_in[0];
  const float* wte = (const float*)d_in[1];
  const float* wpe = (const float*)d_in[2];
  const float* ln1_g = (const float*)d_in[3];
  const float* ln1_b = (const float*)d_in[4];
  const float* wq = (const float*)d_in[5];
  const float* bq = (const float*)d_in[6];
  const float* wk = (const float*)d_in[7];
  const float* bk = (const float*)d_in[8];
  const float* wv = (const float*)d_in[9];
  const float* bv = (const float*)d_in[10];
  const float* wo = (const float*)d_in[11];
  const float* bo = (const float*)d_in[12];
  const float* ln2_g = (const float*)d_in[13];
  const float* ln2_b = (const float*)d_in[14];
  const float* w1 = (const float*)d_in[15];
  const float* b1 = (const float*)d_in[16];
  const float* w2 = (const float*)d_in[17];
  const float* b2 = (const float*)d_in[18];
  const float* lnf_g = (const float*)d_in[19];
  const float* lnf_b = (const float*)d_in[20];
  const float* lm_w = (const float*)d_in[21];
  float* out = (float*)d_out;

  char* p = (char*)d_ws;
  auto alloc = [&](size_t bytes) {
    char* r = p;
    p += (bytes + 255) & ~(size_t)255;
    return r;
  };
  short* lmT   = (short*)alloc((size_t)50304 * 768 * 2);
  float* x     = (float*)alloc((size_t)4096 * 768 * 4);
  short* h     = (short*)alloc((size_t)4096 * 768 * 2);
  short* qb    = (short*)alloc((size_t)4096 * 768 * 2);
  short* kb    = (short*)alloc((size_t)4096 * 768 * 2);
  short* vtb   = (short*)alloc((size_t)4096 * 768 * 2);
  short* ob    = (short*)alloc((size_t)4096 * 768 * 2);
  short* ff    = (short*)alloc((size_t)4096 * 3072 * 2);
  short* wqkvT = (short*)alloc((size_t)2304 * 768 * 2);
  short* woT   = (short*)alloc((size_t)768 * 768 * 2);
  short* w1T   = (short*)alloc((size_t)3072 * 768 * 2);
  short* w2T   = (short*)alloc((size_t)768 * 3072 * 2);
  if ((size_t)(p - (char*)d_ws) > ws_size) return;  // insufficient workspace

  const dim3 tb(32, 8);
  // LM head weight: [768][50257] -> bf16 [50304][768]
  transpose_convert<<<dim3(50304 / 32, 768 / 32), tb, 0, stream>>>(lm_w, lmT, 768, 50257, 50304);
  embed_kernel<<<4096, 256, 0, stream>>>(idx, wte, wpe, x);

  for (int l = 0; l < 12; ++l) {
    const size_t dd = (size_t)768 * 768;
    transpose_convert<<<dim3(24, 24), tb, 0, stream>>>(wq + l * dd, wqkvT, 768, 768, 768);
    transpose_convert<<<dim3(24, 24), tb, 0, stream>>>(wk + l * dd, wqkvT + dd, 768, 768, 768);
    transpose_convert<<<dim3(24, 24), tb, 0, stream>>>(wv + l * dd, wqkvT + 2 * dd, 768, 768, 768);
    transpose_convert<<<dim3(24, 24), tb, 0, stream>>>(wo + l * dd, woT, 768, 768, 768);
    transpose_convert<<<dim3(96, 24), tb, 0, stream>>>(w1 + (size_t)l * 768 * 3072, w1T, 768, 3072, 3072);
    transpose_convert<<<dim3(24, 96), tb, 0, stream>>>(w2 + (size_t)l * 3072 * 768, w2T, 3072, 768, 768);

    ln_kernel<<<4096, 256, 0, stream>>>(x, ln1_g + l * 768, ln1_b + l * 768, h);
    gemm_kernel<EPI_QKV><<<dim3(32, 18), 256, 0, stream>>>(
        h, wqkvT, 768, bq + l * 768, bk + l * 768, bv + l * 768, nullptr, qb, kb, vtb);
    attn_kernel<<<dim3(48, 16), 256, 0, stream>>>(qb, kb, vtb, ob);
    gemm_kernel<EPI_RESID><<<dim3(32, 6), 256, 0, stream>>>(
        ob, woT, 768, bo + l * 768, nullptr, nullptr, x, nullptr, nullptr, nullptr);
    ln_kernel<<<4096, 256, 0, stream>>>(x, ln2_g + l * 768, ln2_b + l * 768, h);
    gemm_kernel<EPI_GELU><<<dim3(32, 24), 256, 0, stream>>>(
        h, w1T, 768, b1 + l * 3072, nullptr, nullptr, nullptr, ff, nullptr, nullptr);
    gemm_kernel<EPI_RESID><<<dim3(32, 6), 256, 0, stream>>>(
        ff, w2T, 3072, b2 + l * 768, nullptr, nullptr, x, nullptr, nullptr, nullptr);
  }

  ln_kernel<<<4096, 256, 0, stream>>>(x, lnf_g, lnf_b, h);
  gemm_kernel<EPI_LM><<<dim3(32, 393), 256, 0, stream>>>(
      h, lmT, 768, nullptr, nullptr, nullptr, out, nullptr, nullptr, nullptr);
}